// Round 7
// baseline (144.993 us; speedup 1.0000x reference)
//
#include <hip/hip_runtime.h>
#include <cstddef>

namespace {
constexpr int B_   = 128;
constexpr int HW   = 65536;        // 256*256
constexpr int EMB_ = 64;
constexpr int NF   = EMB_ + 18;    // 82
constexpr int BNF  = B_ * NF;      // 10496  ([n][m] layout)
constexpr int KCH  = 256;          // k-chunks (encoder grid)
constexpr int KC   = HW / KCH;     // 256 k per block
constexpr int NSTEP = KC / 32;     // 8 steps of 32 k
constexpr int WPITCH = 40;         // wT row pitch in bf16 (32 + 8 pad)
}

typedef short  s16x4 __attribute__((ext_vector_type(4)));
typedef float  f32x4 __attribute__((ext_vector_type(4)));

__device__ __forceinline__ unsigned short bf16rn(float f) {
    unsigned u = __float_as_uint(f);
    u += 0x7FFFu + ((u >> 16) & 1u);
    return (unsigned short)(u >> 16);
}
__device__ __forceinline__ float bf16tof(unsigned short h) {
    return __uint_as_float(((unsigned)h) << 16);
}
__device__ __forceinline__ float ldpix(const unsigned short* p) { return bf16tof(*p); }
__device__ __forceinline__ float ldpix(const float* p)          { return *p; }
__device__ __forceinline__ void  stpix(unsigned short* p, float v) { *p = bf16rn(v); }
__device__ __forceinline__ void  stpix(float* p, float v)          { *p = v; }

// ---------------- Encoder: split-K bf16 MFMA ----------------
// 256 blocks x 512 thr (8 waves). Block = 128m x 82n partial over 256-k chunk.
// Wave wv owns m-subtile [wv*16, wv*16+16). x global->regs, double-buffered
// across steps. Wenc staged transposed bf16 hi/lo in LDS.
// n-tiles 0..3 (emb): hi*hi only. n-tiles 4,5 (theta): 3-term split.
__global__ __launch_bounds__(512) void enc_mfma_k(
    const float* __restrict__ x, const float* __restrict__ Wenc,
    float* __restrict__ partialT)
{
    __shared__ __align__(16) unsigned short wH[96 * WPITCH];  // 7.5 KB
    __shared__ __align__(16) unsigned short wL[96 * WPITCH];  // 7.5 KB

    const int tid  = threadIdx.x;
    const int lane = tid & 63;
    const int wv   = tid >> 6;          // 0..7
    const int ln15 = lane & 15;
    const int lg   = lane >> 4;         // 0..3
    const int m0   = wv << 4;
    const int kblk = blockIdx.x * KC;
    const float* __restrict__ xrow = x + (size_t)(m0 + ln15) * HW + kblk;

    f32x4 acc[6];
#pragma unroll
    for (int t = 0; t < 6; ++t) acc[t] = (f32x4){0.f, 0.f, 0.f, 0.f};

    float4 xa = *reinterpret_cast<const float4*>(&xrow[lg * 4]);
    float4 xb = *reinterpret_cast<const float4*>(&xrow[16 + lg * 4]);

    for (int step = 0; step < NSTEP; ++step) {
        __syncthreads();   // prior step's LDS reads complete before overwrite
        // stage Wenc[32 rows x 82] -> wH/wL [n][kk], vectorized contiguous reads
        {
            const float4* wsrc = reinterpret_cast<const float4*>(
                Wenc + (size_t)(kblk + step * 32) * NF);
            for (int i4 = tid; i4 < (32 * NF) / 4; i4 += 512) {
                const float4 w4 = wsrc[i4];
                const float wv4[4] = {w4.x, w4.y, w4.z, w4.w};
#pragma unroll
                for (int j = 0; j < 4; ++j) {
                    const int idx = i4 * 4 + j;
                    const int kk  = idx / NF;
                    const int n   = idx - kk * NF;
                    const unsigned short hi = bf16rn(wv4[j]);
                    wH[n * WPITCH + kk] = hi;
                    wL[n * WPITCH + kk] = bf16rn(wv4[j] - bf16tof(hi));
                }
            }
        }
        // prefetch next step's x (independent of LDS; overlaps compute)
        float4 xa1, xb1;
        if (step + 1 < NSTEP) {
            xa1 = *reinterpret_cast<const float4*>(&xrow[(step + 1) * 32 + lg * 4]);
            xb1 = *reinterpret_cast<const float4*>(&xrow[(step + 1) * 32 + 16 + lg * 4]);
        }
        __syncthreads();

        s16x4 bh[2], bl[2];
        {
            const float xv[8] = {xa.x, xa.y, xa.z, xa.w, xb.x, xb.y, xb.z, xb.w};
#pragma unroll
            for (int s = 0; s < 2; ++s)
#pragma unroll
                for (int j = 0; j < 4; ++j) {
                    const float v = xv[s * 4 + j];
                    const unsigned short hi = bf16rn(v);
                    bh[s][j] = (short)hi;
                    bl[s][j] = (short)bf16rn(v - bf16tof(hi));
                }
        }

#pragma unroll
        for (int s = 0; s < 2; ++s) {
#pragma unroll
            for (int t = 0; t < 6; ++t) {
                const int aoff = (t * 16 + ln15) * WPITCH + s * 16 + lg * 4;
                const s16x4 ah = *reinterpret_cast<const s16x4*>(&wH[aoff]);
                acc[t] = __builtin_amdgcn_mfma_f32_16x16x16bf16_1k(
                    ah, bh[s], acc[t], 0, 0, 0);
                if (t >= 4) {
                    const s16x4 al = *reinterpret_cast<const s16x4*>(&wL[aoff]);
                    acc[t] = __builtin_amdgcn_mfma_f32_16x16x16bf16_1k(
                        ah, bl[s], acc[t], 0, 0, 0);
                    acc[t] = __builtin_amdgcn_mfma_f32_16x16x16bf16_1k(
                        al, bh[s], acc[t], 0, 0, 0);
                }
            }
        }
        if (step + 1 < NSTEP) { xa = xa1; xb = xb1; }
    }

    float* __restrict__ base = partialT + (size_t)blockIdx.x * BNF;
#pragma unroll
    for (int t = 0; t < 5; ++t)
#pragma unroll
        for (int r = 0; r < 4; ++r) {
            const int n = t * 16 + lg * 4 + r;
            base[(size_t)n * B_ + m0 + ln15] = acc[t][r];
        }
    if (lg == 0) {
#pragma unroll
        for (int r = 0; r < 2; ++r)
            base[(size_t)(80 + r) * B_ + m0 + ln15] = acc[5][r];
    }
}

// ---------------- Encoder reduce (single kernel): 256 -> 1 (+bias) ----------
// 82 blocks x 1024 thr. Thread (g,m): group g sums 32 chunks for column m of
// feature row n=blockIdx.x; 8-group LDS tree finishes.
__global__ __launch_bounds__(1024) void enc_reduce(
    const float* __restrict__ partialT, const float* __restrict__ benc,
    float* __restrict__ featsT)
{
    __shared__ float red[8][128];
    const int n = blockIdx.x;
    const int m = threadIdx.x & 127;
    const int g = threadIdx.x >> 7;      // 0..7
    const float* p = partialT + (size_t)(g * 32) * BNF + (size_t)n * B_ + m;
    float s = 0.f;
#pragma unroll 8
    for (int c = 0; c < 32; ++c) s += p[(size_t)c * BNF];
    red[g][m] = s;
    __syncthreads();
    if (g == 0) {
        float t = benc[n];
#pragma unroll
        for (int j = 0; j < 8; ++j) t += red[j][m];
        featsT[(size_t)n * B_ + m] = t;
    }
}

// ---------------- Decoder GEMM: pred = emb @ W_dec + b_dec (bf16 out) -------
// 1024 blocks x 512 thr: full 128 m x 64-col tile. Wdec read exactly once.
__global__ __launch_bounds__(512) void decoder_k(
    const float* __restrict__ featsT, const float* __restrict__ Wdec,
    const float* __restrict__ bdec, unsigned short* __restrict__ pred)
{
    __shared__ float embT[EMB_ * B_];   // 32 KB, [k*128+m]
    const int tid = threadIdx.x;
    for (int i = tid; i < EMB_ * B_; i += 512) embT[i] = featsT[i];
    __syncthreads();

    const int tp = tid & 15;
    const int tm = tid >> 4;                 // 0..31
    const int p0 = blockIdx.x * 64 + tp * 4;
    const int m0 = tm * 4;

    float acc[4][4];
#pragma unroll
    for (int i = 0; i < 4; ++i)
#pragma unroll
        for (int q = 0; q < 4; ++q) acc[i][q] = 0.f;

#pragma unroll 4
    for (int k = 0; k < EMB_; ++k) {
        const float4 w = *reinterpret_cast<const float4*>(&Wdec[(size_t)k * HW + p0]);
        float e[4];
#pragma unroll
        for (int i = 0; i < 4; ++i) e[i] = embT[k * B_ + m0 + i];
#pragma unroll
        for (int i = 0; i < 4; ++i) {
            acc[i][0] = fmaf(e[i], w.x, acc[i][0]);
            acc[i][1] = fmaf(e[i], w.y, acc[i][1]);
            acc[i][2] = fmaf(e[i], w.z, acc[i][2]);
            acc[i][3] = fmaf(e[i], w.w, acc[i][3]);
        }
    }
    const float4 bd = *reinterpret_cast<const float4*>(&bdec[p0]);
#pragma unroll
    for (int i = 0; i < 4; ++i) {
        ushort4 o;
        o.x = bf16rn(acc[i][0] + bd.x);
        o.y = bf16rn(acc[i][1] + bd.y);
        o.z = bf16rn(acc[i][2] + bd.z);
        o.w = bf16rn(acc[i][3] + bd.w);
        *reinterpret_cast<ushort4*>(&pred[(size_t)(m0 + i) * HW + p0]) = o;
    }
}

// ---------------- Bilinear affine grid-sample, 2D-tiled ----------------
// Block = 16x16 output tile; wave = 16x4 sub-tile (minimizes distinct cache
// lines per gather under rotation/shear). XCD-chunked swizzle: XCD k owns
// images [16k,16k+16) at every stage -> producer/consumer L2 locality.
template <typename TI, typename TO>
__global__ __launch_bounds__(256) void gsample_k(
    const TI* __restrict__ src, TO* __restrict__ dst,
    const float* __restrict__ featsT, int theta_sel)
{
    const int bid  = ((blockIdx.x & 7) << 12) | (blockIdx.x >> 3);  // bijective
    const int b    = bid >> 8;
    const int tile = bid & 255;
    const int tx0  = (tile & 15) << 4;
    const int ty0  = (tile >> 4) << 4;
    const int lane = threadIdx.x & 63;
    const int wv   = threadIdx.x >> 6;
    const int xq   = tx0 + (lane & 15);
    const int y    = ty0 + (wv << 2) + (lane >> 4);

    const int tb = EMB_ + theta_sel * 6;
    const float t00 = featsT[(size_t)(tb + 0) * B_ + b];
    const float t01 = featsT[(size_t)(tb + 1) * B_ + b];
    const float t02 = featsT[(size_t)(tb + 2) * B_ + b];
    const float t10 = featsT[(size_t)(tb + 3) * B_ + b];
    const float t11 = featsT[(size_t)(tb + 4) * B_ + b];
    const float t12 = featsT[(size_t)(tb + 5) * B_ + b];

    const float X = (float)(2 * xq + 1) * (1.f / 256.f) - 1.f;
    const float Y = (float)(2 * y  + 1) * (1.f / 256.f) - 1.f;

    const float gx = t00 * X + t01 * Y + t02;
    const float gy = t10 * X + t11 * Y + t12;

    const float ix = (gx + 1.f) * 128.f - 0.5f;
    const float iy = (gy + 1.f) * 128.f - 0.5f;
    const float ix0 = floorf(ix);
    const float iy0 = floorf(iy);
    const float wx1 = ix - ix0, wx0 = 1.f - wx1;
    const float wy1 = iy - iy0, wy0 = 1.f - wy1;

    const TI* sb = src + ((size_t)b << 16);
    auto tap = [&](float xf, float yf) -> float {
        const bool valid = (xf >= 0.f) && (xf < 256.f) &&
                           (yf >= 0.f) && (yf < 256.f);
        const int xi = (int)fminf(fmaxf(xf, 0.f), 255.f);
        const int yi = (int)fminf(fmaxf(yf, 0.f), 255.f);
        const float v = ldpix(sb + (yi << 8) + xi);
        return valid ? v : 0.f;
    };
    const float v00 = tap(ix0,       iy0);
    const float v10 = tap(ix0 + 1.f, iy0);
    const float v01 = tap(ix0,       iy0 + 1.f);
    const float v11 = tap(ix0 + 1.f, iy0 + 1.f);

    stpix(dst + ((size_t)b << 16) + (y << 8) + xq,
          v00 * (wx0 * wy0) + v10 * (wx1 * wy0) +
          v01 * (wx0 * wy1) + v11 * (wx1 * wy1));
}

extern "C" void kernel_launch(void* const* d_in, const int* in_sizes, int n_in,
                              void* d_out, int out_size, void* d_ws, size_t ws_size,
                              hipStream_t stream)
{
    const float* x    = (const float*)d_in[0];
    const float* Wenc = (const float*)d_in[1];
    const float* benc = (const float*)d_in[2];
    const float* Wdec = (const float*)d_in[3];
    const float* bdec = (const float*)d_in[4];
    float* out = (float*)d_out;

    char* wsb = (char*)d_ws;
    float* partialT       = (float*)wsb;                          // 10.7 MB (dead after enc_reduce)
    unsigned short* imgB0 = (unsigned short*)wsb;                 // 16.7 MB (written after partialT dead)
    unsigned short* imgB1 = (unsigned short*)(wsb + (20u << 20)); // 16.7 MB
    float* featsT         = (float*)(wsb + (40u << 20));          // 41 KB

    enc_mfma_k<<<KCH, 512, 0, stream>>>(x, Wenc, partialT);
    enc_reduce<<<NF, 1024, 0, stream>>>(partialT, benc, featsT);
    decoder_k<<<1024, 512, 0, stream>>>(featsT, Wdec, bdec, imgB0);
    // reference order: grid_3 (translation=2), grid_1 (scaler_shear=0), grid_2 (rotation=1)
    gsample_k<unsigned short, unsigned short>
        <<<B_ * 256, 256, 0, stream>>>(imgB0, imgB1, featsT, 2);
    gsample_k<unsigned short, unsigned short>
        <<<B_ * 256, 256, 0, stream>>>(imgB1, imgB0, featsT, 0);
    gsample_k<unsigned short, float>
        <<<B_ * 256, 256, 0, stream>>>(imgB0, out, featsT, 1);
}

// Round 8
// 106.135 us; speedup vs baseline: 1.3661x; 1.3661x over previous
//
#include <hip/hip_runtime.h>
#include <cstddef>

namespace {
constexpr int B_   = 128;
constexpr int HW   = 65536;        // 256*256
constexpr int EMB_ = 64;
constexpr int NF   = EMB_ + 18;    // 82
constexpr int BNF  = B_ * NF;      // 10496  ([n][m] layout)
constexpr int KCH  = 256;          // k-chunks (encoder grid)
constexpr int KC   = HW / KCH;     // 256 k per block
constexpr int NSTEP = KC / 32;     // 8 steps of 32 k
constexpr int WPITCH = 40;         // wT row pitch in bf16 (32 + 8 pad)
constexpr int IPITCH = 260;        // LDS image row pitch in bf16 (2-bank/row rotate, 8B-aligned)
constexpr size_t GS_LDS = (size_t)256 * IPITCH * 2;  // 133120 B
}

typedef short  s16x4 __attribute__((ext_vector_type(4)));
typedef float  f32x4 __attribute__((ext_vector_type(4)));

__device__ __forceinline__ unsigned short bf16rn(float f) {
    unsigned u = __float_as_uint(f);
    u += 0x7FFFu + ((u >> 16) & 1u);
    return (unsigned short)(u >> 16);
}
__device__ __forceinline__ float bf16tof(unsigned short h) {
    return __uint_as_float(((unsigned)h) << 16);
}
__device__ __forceinline__ void stpix(unsigned short* p, float v) { *p = bf16rn(v); }
__device__ __forceinline__ void stpix(float* p, float v)          { *p = v; }

// ---------------- Encoder: split-K bf16 MFMA ----------------
__global__ __launch_bounds__(512) void enc_mfma_k(
    const float* __restrict__ x, const float* __restrict__ Wenc,
    float* __restrict__ partialT)
{
    __shared__ __align__(16) unsigned short wH[96 * WPITCH];  // 7.5 KB
    __shared__ __align__(16) unsigned short wL[96 * WPITCH];  // 7.5 KB

    const int tid  = threadIdx.x;
    const int lane = tid & 63;
    const int wv   = tid >> 6;          // 0..7
    const int ln15 = lane & 15;
    const int lg   = lane >> 4;         // 0..3
    const int m0   = wv << 4;
    const int kblk = blockIdx.x * KC;
    const float* __restrict__ xrow = x + (size_t)(m0 + ln15) * HW + kblk;

    f32x4 acc[6];
#pragma unroll
    for (int t = 0; t < 6; ++t) acc[t] = (f32x4){0.f, 0.f, 0.f, 0.f};

    float4 xa = *reinterpret_cast<const float4*>(&xrow[lg * 4]);
    float4 xb = *reinterpret_cast<const float4*>(&xrow[16 + lg * 4]);

    for (int step = 0; step < NSTEP; ++step) {
        __syncthreads();
        {
            const float4* wsrc = reinterpret_cast<const float4*>(
                Wenc + (size_t)(kblk + step * 32) * NF);
            for (int i4 = tid; i4 < (32 * NF) / 4; i4 += 512) {
                const float4 w4 = wsrc[i4];
                const float wv4[4] = {w4.x, w4.y, w4.z, w4.w};
#pragma unroll
                for (int j = 0; j < 4; ++j) {
                    const int idx = i4 * 4 + j;
                    const int kk  = idx / NF;
                    const int n   = idx - kk * NF;
                    const unsigned short hi = bf16rn(wv4[j]);
                    wH[n * WPITCH + kk] = hi;
                    wL[n * WPITCH + kk] = bf16rn(wv4[j] - bf16tof(hi));
                }
            }
        }
        float4 xa1, xb1;
        if (step + 1 < NSTEP) {
            xa1 = *reinterpret_cast<const float4*>(&xrow[(step + 1) * 32 + lg * 4]);
            xb1 = *reinterpret_cast<const float4*>(&xrow[(step + 1) * 32 + 16 + lg * 4]);
        }
        __syncthreads();

        s16x4 bh[2], bl[2];
        {
            const float xv[8] = {xa.x, xa.y, xa.z, xa.w, xb.x, xb.y, xb.z, xb.w};
#pragma unroll
            for (int s = 0; s < 2; ++s)
#pragma unroll
                for (int j = 0; j < 4; ++j) {
                    const float v = xv[s * 4 + j];
                    const unsigned short hi = bf16rn(v);
                    bh[s][j] = (short)hi;
                    bl[s][j] = (short)bf16rn(v - bf16tof(hi));
                }
        }

#pragma unroll
        for (int s = 0; s < 2; ++s) {
#pragma unroll
            for (int t = 0; t < 6; ++t) {
                const int aoff = (t * 16 + ln15) * WPITCH + s * 16 + lg * 4;
                const s16x4 ah = *reinterpret_cast<const s16x4*>(&wH[aoff]);
                acc[t] = __builtin_amdgcn_mfma_f32_16x16x16bf16_1k(
                    ah, bh[s], acc[t], 0, 0, 0);
                if (t >= 4) {
                    const s16x4 al = *reinterpret_cast<const s16x4*>(&wL[aoff]);
                    acc[t] = __builtin_amdgcn_mfma_f32_16x16x16bf16_1k(
                        ah, bl[s], acc[t], 0, 0, 0);
                    acc[t] = __builtin_amdgcn_mfma_f32_16x16x16bf16_1k(
                        al, bh[s], acc[t], 0, 0, 0);
                }
            }
        }
        if (step + 1 < NSTEP) { xa = xa1; xb = xb1; }
    }

    float* __restrict__ base = partialT + (size_t)blockIdx.x * BNF;
#pragma unroll
    for (int t = 0; t < 5; ++t)
#pragma unroll
        for (int r = 0; r < 4; ++r) {
            const int n = t * 16 + lg * 4 + r;
            base[(size_t)n * B_ + m0 + ln15] = acc[t][r];
        }
    if (lg == 0) {
#pragma unroll
        for (int r = 0; r < 2; ++r)
            base[(size_t)(80 + r) * B_ + m0 + ln15] = acc[5][r];
    }
}

// ---------------- Encoder reduce: 256 -> 1 (+bias) ----------------
__global__ __launch_bounds__(1024) void enc_reduce(
    const float* __restrict__ partialT, const float* __restrict__ benc,
    float* __restrict__ featsT)
{
    __shared__ float red[8][128];
    const int n = blockIdx.x;
    const int m = threadIdx.x & 127;
    const int g = threadIdx.x >> 7;      // 0..7
    const float* p = partialT + (size_t)(g * 32) * BNF + (size_t)n * B_ + m;
    float s = 0.f;
#pragma unroll 8
    for (int c = 0; c < 32; ++c) s += p[(size_t)c * BNF];
    red[g][m] = s;
    __syncthreads();
    if (g == 0) {
        float t = benc[n];
#pragma unroll
        for (int j = 0; j < 8; ++j) t += red[j][m];
        featsT[(size_t)n * B_ + m] = t;
    }
}

// ---------------- Decoder GEMM: pred = emb @ W_dec + b_dec (bf16 out) -------
__global__ __launch_bounds__(512) void decoder_k(
    const float* __restrict__ featsT, const float* __restrict__ Wdec,
    const float* __restrict__ bdec, unsigned short* __restrict__ pred)
{
    __shared__ float embT[EMB_ * B_];   // 32 KB, [k*128+m]
    const int tid = threadIdx.x;
    for (int i = tid; i < EMB_ * B_; i += 512) embT[i] = featsT[i];
    __syncthreads();

    const int tp = tid & 15;
    const int tm = tid >> 4;                 // 0..31
    const int p0 = blockIdx.x * 64 + tp * 4;
    const int m0 = tm * 4;

    float acc[4][4];
#pragma unroll
    for (int i = 0; i < 4; ++i)
#pragma unroll
        for (int q = 0; q < 4; ++q) acc[i][q] = 0.f;

#pragma unroll 4
    for (int k = 0; k < EMB_; ++k) {
        const float4 w = *reinterpret_cast<const float4*>(&Wdec[(size_t)k * HW + p0]);
        float e[4];
#pragma unroll
        for (int i = 0; i < 4; ++i) e[i] = embT[k * B_ + m0 + i];
#pragma unroll
        for (int i = 0; i < 4; ++i) {
            acc[i][0] = fmaf(e[i], w.x, acc[i][0]);
            acc[i][1] = fmaf(e[i], w.y, acc[i][1]);
            acc[i][2] = fmaf(e[i], w.z, acc[i][2]);
            acc[i][3] = fmaf(e[i], w.w, acc[i][3]);
        }
    }
    const float4 bd = *reinterpret_cast<const float4*>(&bdec[p0]);
#pragma unroll
    for (int i = 0; i < 4; ++i) {
        ushort4 o;
        o.x = bf16rn(acc[i][0] + bd.x);
        o.y = bf16rn(acc[i][1] + bd.y);
        o.z = bf16rn(acc[i][2] + bd.z);
        o.w = bf16rn(acc[i][3] + bd.w);
        *reinterpret_cast<ushort4*>(&pred[(size_t)(m0 + i) * HW + p0]) = o;
    }
}

// ---------------- Grid-sample: whole source image staged in LDS ----------------
// 256 blocks x 1024 thr. Block = one output half-image; stages the FULL
// 256x256 bf16 source (128 KB -> 133 KB padded) into LDS coalesced, then
// does the 4 bilinear taps as ds_read_u16 (LDS pipe, not the TA gather path).
// Pitch 260 rotates banks 2/row. Swizzle pairs (p, p+8) onto one image so
// both halves' staging reads hit the same XCD's L2.
template <typename TO>
__global__ __launch_bounds__(1024) void gsample_lds(
    const unsigned short* __restrict__ src, TO* __restrict__ dst,
    const float* __restrict__ featsT, int theta_sel)
{
    extern __shared__ unsigned short simg[];   // [256][IPITCH]

    const int p    = blockIdx.x;
    const int b    = ((p >> 4) << 3) | (p & 7);
    const int half = (p >> 3) & 1;
    const int tid  = threadIdx.x;

    // stage full image: 16384 ushort4, 16 per thread, coalesced
    const unsigned short* __restrict__ sb = src + ((size_t)b << 16);
    {
        const ushort4* __restrict__ s4 = reinterpret_cast<const ushort4*>(sb);
#pragma unroll
        for (int it = 0; it < 16; ++it) {
            const int i = tid + (it << 10);
            const int r  = i >> 6;
            const int c4 = i & 63;
            *reinterpret_cast<ushort4*>(&simg[r * IPITCH + (c4 << 2)]) = s4[i];
        }
    }

    const int tb = EMB_ + theta_sel * 6;
    const float t00 = featsT[(size_t)(tb + 0) * B_ + b];
    const float t01 = featsT[(size_t)(tb + 1) * B_ + b];
    const float t02 = featsT[(size_t)(tb + 2) * B_ + b];
    const float t10 = featsT[(size_t)(tb + 3) * B_ + b];
    const float t11 = featsT[(size_t)(tb + 4) * B_ + b];
    const float t12 = featsT[(size_t)(tb + 5) * B_ + b];

    __syncthreads();

    TO* __restrict__ db = dst + ((size_t)b << 16) + ((size_t)half << 15);

#pragma unroll 2
    for (int it = 0; it < 32; ++it) {
        const int px = (it << 10) + tid;        // 0..32767 within half
        const int y  = (half << 7) + (px >> 8);
        const int xq = px & 255;

        const float X = (float)(2 * xq + 1) * (1.f / 256.f) - 1.f;
        const float Y = (float)(2 * y  + 1) * (1.f / 256.f) - 1.f;

        const float gx = t00 * X + t01 * Y + t02;
        const float gy = t10 * X + t11 * Y + t12;

        const float ix = (gx + 1.f) * 128.f - 0.5f;
        const float iy = (gy + 1.f) * 128.f - 0.5f;
        const float ix0 = floorf(ix);
        const float iy0 = floorf(iy);
        const float wx1 = ix - ix0, wx0 = 1.f - wx1;
        const float wy1 = iy - iy0, wy0 = 1.f - wy1;

        auto tap = [&](float xf, float yf) -> float {
            const bool valid = (xf >= 0.f) && (xf < 256.f) &&
                               (yf >= 0.f) && (yf < 256.f);
            const int xi = (int)fminf(fmaxf(xf, 0.f), 255.f);
            const int yi = (int)fminf(fmaxf(yf, 0.f), 255.f);
            const float v = bf16tof(simg[yi * IPITCH + xi]);
            return valid ? v : 0.f;
        };
        const float v00 = tap(ix0,       iy0);
        const float v10 = tap(ix0 + 1.f, iy0);
        const float v01 = tap(ix0,       iy0 + 1.f);
        const float v11 = tap(ix0 + 1.f, iy0 + 1.f);

        stpix(db + px,
              v00 * (wx0 * wy0) + v10 * (wx1 * wy0) +
              v01 * (wx0 * wy1) + v11 * (wx1 * wy1));
    }
}

extern "C" void kernel_launch(void* const* d_in, const int* in_sizes, int n_in,
                              void* d_out, int out_size, void* d_ws, size_t ws_size,
                              hipStream_t stream)
{
    const float* x    = (const float*)d_in[0];
    const float* Wenc = (const float*)d_in[1];
    const float* benc = (const float*)d_in[2];
    const float* Wdec = (const float*)d_in[3];
    const float* bdec = (const float*)d_in[4];
    float* out = (float*)d_out;

    char* wsb = (char*)d_ws;
    float* partialT       = (float*)wsb;                          // 10.7 MB (dead after enc_reduce)
    unsigned short* imgB0 = (unsigned short*)wsb;                 // 16.7 MB (written after partialT dead)
    unsigned short* imgB1 = (unsigned short*)(wsb + (20u << 20)); // 16.7 MB
    float* featsT         = (float*)(wsb + (40u << 20));          // 41 KB

    // opt-in to >64KB dynamic LDS (deterministic, idempotent, not a stream op)
    (void)hipFuncSetAttribute((const void*)gsample_lds<unsigned short>,
        hipFuncAttributeMaxDynamicSharedMemorySize, (int)GS_LDS);
    (void)hipFuncSetAttribute((const void*)gsample_lds<float>,
        hipFuncAttributeMaxDynamicSharedMemorySize, (int)GS_LDS);

    enc_mfma_k<<<KCH, 512, 0, stream>>>(x, Wenc, partialT);
    enc_reduce<<<NF, 1024, 0, stream>>>(partialT, benc, featsT);
    decoder_k<<<1024, 512, 0, stream>>>(featsT, Wdec, bdec, imgB0);
    // reference order: grid_3 (translation=2), grid_1 (scaler_shear=0), grid_2 (rotation=1)
    gsample_lds<unsigned short><<<256, 1024, GS_LDS, stream>>>(imgB0, imgB1, featsT, 2);
    gsample_lds<unsigned short><<<256, 1024, GS_LDS, stream>>>(imgB1, imgB0, featsT, 0);
    gsample_lds<float>         <<<256, 1024, GS_LDS, stream>>>(imgB0, out,  featsT, 1);
}